// Round 6
// baseline (1497.649 us; speedup 1.0000x reference)
//
#include <hip/hip_runtime.h>

#define B_ 2
#define N_ 1024
#define C_ 1024
#define H_ 16
#define HD_ 64

// ---------- wave-wide (64-lane) helpers ----------
__device__ __forceinline__ float wsumf(float x) {
#pragma unroll
  for (int off = 32; off; off >>= 1) x += __shfl_xor(x, off, 64);
  return x;
}
// order-preserving float->uint map (total order matches float compare for non-NaN)
__device__ __forceinline__ unsigned orderu(float f) {
  unsigned b = __float_as_uint(f);
  return (b & 0x80000000u) ? ~b : (b | 0x80000000u);
}
__device__ __forceinline__ float iorderu(unsigned x) {
  unsigned b = (x & 0x80000000u) ? (x & 0x7FFFFFFFu) : ~x;
  return __uint_as_float(b);
}

// ---------- NKAT per-token factor ----------
__global__ __launch_bounds__(64) void factor_kernel(
    const float* __restrict__ x, const float* __restrict__ alpha_p,
    const float* __restrict__ beta_p, float* __restrict__ fac) {
  const int row = blockIdx.x;  // b*N + n
  const int lane = threadIdx.x;
  const float4* xr = (const float4*)(x + (size_t)row * C_);
  float s = 0.f, ss = 0.f;
#pragma unroll
  for (int j = 0; j < 4; ++j) {
    float4 v = xr[lane + 64 * j];
    s += v.x + v.y + v.z + v.w;
    ss += v.x * v.x + v.y * v.y + v.z * v.z + v.w * v.w;
  }
  s = wsumf(s);
  ss = wsumf(ss);
  const float mean = s * (1.f / 1024.f);
  const float var = ss * (1.f / 1024.f) - mean * mean;
  const float theta =
      alpha_p[0] * tanhf(mean) + beta_p[0] * (1.f / (1.f + __expf(-var)));
  if (lane == 0) fac[row] = 1.f + 0.45125f * theta;  // lc = 0.5*0.95^2
}

// ---------- shared f32 GEMM core: 128x128 tile, 256 thr, 8x8/thread, BK=8 ----------
__device__ __forceinline__ void gemm_core(const float* __restrict__ A,
                                          const float* __restrict__ Bm, int K,
                                          int N, int m0, int n0,
                                          float* __restrict__ a_lds,
                                          float* __restrict__ b_lds,
                                          float acc[8][8]) {
  const int tid = threadIdx.x;
  const int tx = tid & 15, ty = tid >> 4;
  const int r = tid >> 1, c4 = (tid & 1) << 2;     // A tile: 128 rows x 8 cols
  const int rb = tid >> 5, cb = (tid & 31) << 2;   // B tile: 8 rows x 128 cols
  float4 av = *(const float4*)(A + (size_t)(m0 + r) * K + c4);
  float4 bv = *(const float4*)(Bm + (size_t)rb * N + n0 + cb);
  for (int k0 = 0; k0 < K; k0 += 8) {
    __syncthreads();  // previous iteration's LDS reads done
    a_lds[(c4 + 0) * 128 + r] = av.x;  // store A transposed: [k][m]
    a_lds[(c4 + 1) * 128 + r] = av.y;
    a_lds[(c4 + 2) * 128 + r] = av.z;
    a_lds[(c4 + 3) * 128 + r] = av.w;
    *(float4*)(b_lds + rb * 128 + cb) = bv;
    __syncthreads();
    if (k0 + 8 < K) {  // prefetch next tile; latency hides under FMA phase
      av = *(const float4*)(A + (size_t)(m0 + r) * K + k0 + 8 + c4);
      bv = *(const float4*)(Bm + (size_t)(k0 + 8 + rb) * N + n0 + cb);
    }
#pragma unroll
    for (int kk = 0; kk < 8; ++kk) {
      const float4 a0 = *(const float4*)(a_lds + kk * 128 + ty * 8);
      const float4 a1 = *(const float4*)(a_lds + kk * 128 + ty * 8 + 4);
      const float4 b0 = *(const float4*)(b_lds + kk * 128 + tx * 8);
      const float4 b1 = *(const float4*)(b_lds + kk * 128 + tx * 8 + 4);
      const float af[8] = {a0.x, a0.y, a0.z, a0.w, a1.x, a1.y, a1.z, a1.w};
      const float bf[8] = {b0.x, b0.y, b0.z, b0.w, b1.x, b1.y, b1.z, b1.w};
#pragma unroll
      for (int i = 0; i < 8; ++i)
#pragma unroll
        for (int jj = 0; jj < 8; ++jj)
          acc[i][jj] = fmaf(af[i], bf[jj], acc[i][jj]);
    }
  }
}

// ---------- qkv = x @ w_qkv; Q,V in (B,H,N,HD); K TRANSPOSED: kt[bh][d][n] ----------
__global__ __launch_bounds__(256) void gemm_qkv_kernel(
    const float* __restrict__ x, const float* __restrict__ w,
    float* __restrict__ q, float* __restrict__ kt, float* __restrict__ v) {
  __shared__ __align__(16) float a_lds[8 * 128];
  __shared__ __align__(16) float b_lds[8 * 128];
  float acc[8][8];
#pragma unroll
  for (int i = 0; i < 8; ++i)
#pragma unroll
    for (int jj = 0; jj < 8; ++jj) acc[i][jj] = 0.f;
  const int m0 = blockIdx.y * 128, n0 = blockIdx.x * 128;
  gemm_core(x, w, C_, 3 * C_, m0, n0, a_lds, b_lds, acc);

  const int tx = threadIdx.x & 15, ty = threadIdx.x >> 4;
  const int j0 = n0 + tx * 8;           // 8 consecutive cols: same sel, same head
  const int sel = j0 >> 10;             // 0=q 1=k 2=v
  const int hh = (j0 >> 6) & 15;
  const int d0 = j0 & 63;
  const int bb = m0 >> 10;              // whole 128-row stripe in same batch
  const int nn0 = (m0 & 1023) + ty * 8; // rows nn0..nn0+7 consecutive

  if (sel == 1) {
    // K transposed: kt[((bb*16+hh)*64 + d)*1024 + n]; rows i are consecutive n
#pragma unroll
    for (int jj = 0; jj < 8; ++jj) {
      float* dst = kt + (((size_t)((bb << 4) + hh) * HD_ + d0 + jj) * N_ + nn0);
      *(float4*)dst = make_float4(acc[0][jj], acc[1][jj], acc[2][jj], acc[3][jj]);
      *(float4*)(dst + 4) =
          make_float4(acc[4][jj], acc[5][jj], acc[6][jj], acc[7][jj]);
    }
  } else {
    float* dstbuf = (sel == 0) ? q : v;
#pragma unroll
    for (int i = 0; i < 8; ++i) {
      float* dst = dstbuf + ((((size_t)(bb << 4)) + hh) * N_ + nn0 + i) * HD_ + d0;
      *(float4*)dst = make_float4(acc[i][0], acc[i][1], acc[i][2], acc[i][3]);
      *(float4*)(dst + 4) =
          make_float4(acc[i][4], acc[i][5], acc[i][6], acc[i][7]);
    }
  }
}

// ---------- out = attn_out @ w_out + b_out ----------
__global__ __launch_bounds__(256) void gemm_out_kernel(
    const float* __restrict__ a, const float* __restrict__ w,
    const float* __restrict__ bias, float* __restrict__ out) {
  __shared__ __align__(16) float a_lds[8 * 128];
  __shared__ __align__(16) float b_lds[8 * 128];
  float acc[8][8];
#pragma unroll
  for (int i = 0; i < 8; ++i)
#pragma unroll
    for (int jj = 0; jj < 8; ++jj) acc[i][jj] = 0.f;
  const int m0 = blockIdx.y * 128, n0 = blockIdx.x * 128;
  gemm_core(a, w, C_, C_, m0, n0, a_lds, b_lds, acc);

  const int tx = threadIdx.x & 15, ty = threadIdx.x >> 4;
  const int j0 = n0 + tx * 8;
  const float4 bs0 = *(const float4*)(bias + j0);
  const float4 bs1 = *(const float4*)(bias + j0 + 4);
#pragma unroll
  for (int i = 0; i < 8; ++i) {
    const int mm = m0 + ty * 8 + i;
    float* dst = out + (size_t)mm * C_ + j0;
    *(float4*)dst = make_float4(acc[i][0] + bs0.x, acc[i][1] + bs0.y,
                                acc[i][2] + bs0.z, acc[i][3] + bs0.w);
    *(float4*)(dst + 4) = make_float4(acc[i][4] + bs1.x, acc[i][5] + bs1.y,
                                      acc[i][6] + bs1.z, acc[i][7] + bs1.w);
  }
}

// ---------- attention: 4 waves/block, 4 queries/wave; pipelined K^T scores ----------
// key = pass*256 + lane*4 + jl ; u[q][pass*4+jl] is the selection state.
// Score phase: triple-buffered register prefetch (load chunk c+2 while FMA c).
// PV phase: ping-pong prefetch of v-rows in groups of 4.
__global__ __launch_bounds__(256) void attn_kernel(
    const float* __restrict__ qw, const float* __restrict__ kt,
    const float* __restrict__ vw, const float* __restrict__ fac,
    float* __restrict__ ao) {
  const int lane = threadIdx.x & 63;
  const int wid = threadIdx.x >> 6;
  const int qblk = blockIdx.x * 16;      // 16 queries per block, same (b,h)
  const int bh = qblk >> 10;
  const int b = bh >> 4, h = bh & 15;
  const int q0 = (qblk & (N_ - 1)) + wid * 4;  // first query of this wave

  __shared__ __align__(16) float q_ldsT[4][HD_][4];  // [wave][d][query]
  __shared__ unsigned su[4][64];
  __shared__ float sv[4][64];
  __shared__ int ck[4][64];
  __shared__ float cv[4][64];

  // load this wave's 4 query vectors, store transposed [d][q]; wave-private,
  // DS ops in-order within a wave -> no barrier needed
  {
    const int qq = lane >> 4, dp = (lane & 15) << 2;
    const float4 v =
        *(const float4*)(qw + ((size_t)bh * N_ + q0 + qq) * HD_ + dp);
    q_ldsT[wid][dp + 0][qq] = v.x;
    q_ldsT[wid][dp + 1][qq] = v.y;
    q_ldsT[wid][dp + 2][qq] = v.z;
    q_ldsT[wid][dp + 3][qq] = v.w;
  }

  const float* ktb = kt + ((size_t)bh * HD_ * N_);  // [d][n]
  const unsigned long long ltmask = (1ull << lane) - 1ull;
  unsigned u[4][16];  // [query][pass*4+jl]

  // ---- score phase: coalesced K^T streaming, triple-buffered prefetch ----
  for (int pass = 0; pass < 4; ++pass) {
    float acc[4][4];  // [jl][query]
#pragma unroll
    for (int a = 0; a < 4; ++a)
#pragma unroll
      for (int c = 0; c < 4; ++c) acc[a][c] = 0.f;
    const float* kp = ktb + (pass << 8) + (lane << 2);

    auto ld4 = [&](float4* buf, int c) {
#pragma unroll
      for (int t = 0; t < 4; ++t)
        buf[t] = *(const float4*)(kp + (size_t)(c * 4 + t) * N_);
    };
    auto fm4 = [&](const float4* buf, int c) {
#pragma unroll
      for (int t = 0; t < 4; ++t) {
        const int d = c * 4 + t;
        const float4 kv = buf[t];
        const float4 qv = *(const float4*)(&q_ldsT[wid][d][0]);  // broadcast
        acc[0][0] = fmaf(kv.x, qv.x, acc[0][0]);
        acc[0][1] = fmaf(kv.x, qv.y, acc[0][1]);
        acc[0][2] = fmaf(kv.x, qv.z, acc[0][2]);
        acc[0][3] = fmaf(kv.x, qv.w, acc[0][3]);
        acc[1][0] = fmaf(kv.y, qv.x, acc[1][0]);
        acc[1][1] = fmaf(kv.y, qv.y, acc[1][1]);
        acc[1][2] = fmaf(kv.y, qv.z, acc[1][2]);
        acc[1][3] = fmaf(kv.y, qv.w, acc[1][3]);
        acc[2][0] = fmaf(kv.z, qv.x, acc[2][0]);
        acc[2][1] = fmaf(kv.z, qv.y, acc[2][1]);
        acc[2][2] = fmaf(kv.z, qv.z, acc[2][2]);
        acc[2][3] = fmaf(kv.z, qv.w, acc[2][3]);
        acc[3][0] = fmaf(kv.w, qv.x, acc[3][0]);
        acc[3][1] = fmaf(kv.w, qv.y, acc[3][1]);
        acc[3][2] = fmaf(kv.w, qv.z, acc[3][2]);
        acc[3][3] = fmaf(kv.w, qv.w, acc[3][3]);
      }
    };

    float4 bA[4], bB[4], bC[4];
    ld4(bA, 0);
    ld4(bB, 1);
#pragma unroll
    for (int c = 0; c < 16; ++c) {  // 16 chunks of 4 d; c compile-time
      if (c + 2 < 16) {
        if (((c + 2) % 3) == 0) ld4(bA, c + 2);
        else if (((c + 2) % 3) == 1) ld4(bB, c + 2);
        else ld4(bC, c + 2);
      }
      if ((c % 3) == 0) fm4(bA, c);
      else if ((c % 3) == 1) fm4(bB, c);
      else fm4(bC, c);
    }
#pragma unroll
    for (int jl = 0; jl < 4; ++jl)
#pragma unroll
      for (int q = 0; q < 4; ++q)
        u[q][(pass << 2) + jl] = orderu((acc[jl][q] * 0.125f) / 0.8f);
  }

  // ---- batched wave-max over 4 queries (integer max == float max) ----
  unsigned mu[4];
#pragma unroll
  for (int q = 0; q < 4; ++q) {
    unsigned mq = u[q][0];
#pragma unroll
    for (int j = 1; j < 16; ++j) mq = max(mq, u[q][j]);
    mu[q] = mq;
  }
#pragma unroll
  for (int off = 32; off; off >>= 1) {
#pragma unroll
    for (int q = 0; q < 4; ++q)
      mu[q] = max(mu[q], (unsigned)__shfl_xor((int)mu[q], off, 64));
  }

  // ---- batched top-k binary searches (4 independent chains, lockstep) ----
  unsigned lo[4], hi[4];
#pragma unroll
  for (int q = 0; q < 4; ++q) { lo[q] = 0u; hi[q] = mu[q]; }
  while ((lo[0] < hi[0]) | (lo[1] < hi[1]) | (lo[2] < hi[2]) |
         (lo[3] < hi[3])) {
#pragma unroll
    for (int q = 0; q < 4; ++q) {
      if (lo[q] < hi[q]) {  // wave-uniform condition
        const unsigned mid = lo[q] + ((hi[q] - lo[q]) >> 1) + 1u;
        int c = 0;
#pragma unroll
        for (int j = 0; j < 16; ++j)
          c += (int)__popcll(__ballot(u[q][j] >= mid));
        if (c >= 64) lo[q] = mid; else hi[q] = mid - 1u;
      }
    }
  }

  // ---- per-query: top-p + softmax + PV ----
  const float* vb = vw + ((size_t)bh << 16);
#pragma unroll
  for (int qq = 0; qq < 4; ++qq) {
    const unsigned kthu = lo[qq];
    const float m = iorderu(mu[qq]);

    // exp over kept set (others exactly 0 = exp(NEG-m) underflow)
    float e[16];
    float zl = 0.f;
#pragma unroll
    for (int j = 0; j < 16; ++j) {
      const float ej = (u[qq][j] >= kthu) ? expf(iorderu(u[qq][j]) - m) : 0.f;
      e[j] = ej;
      zl += ej;
    }
    const float Z = wsumf(zl);
    const float limit = 0.9f * Z;  // TOP_P * Z

    // compact survivors (u>=kth; count >= 64 always, so slots 0..63 all fill)
    int base = 0;
#pragma unroll
    for (int j = 0; j < 16; ++j) {
      const bool f = (u[qq][j] >= kthu);
      const unsigned long long mb = __ballot(f);
      if (f) {
        const int pos = base + (int)__popcll(mb & ltmask);
        if (pos < 64) {
          su[wid][pos] = u[qq][j];
          sv[wid][pos] = e[j];
        }
      }
      base += (int)__popcll(mb);
    }

    // bitonic sort across 64 lanes, ascending by ~u (= descending by u)
    unsigned sk = ~su[wid][lane];
    float se = sv[wid][lane];
#pragma unroll
    for (int k = 2; k <= 64; k <<= 1) {
#pragma unroll
      for (int j = k >> 1; j; j >>= 1) {
        const unsigned pk = (unsigned)__shfl_xor((int)sk, j, 64);
        const float pe = __shfl_xor(se, j, 64);
        const bool takeMin = (((lane & j) == 0) == ((lane & k) == 0));
        const bool sw = takeMin ? (pk < sk) : (pk > sk);
        if (sw) { sk = pk; se = pe; }
      }
    }

    // inclusive prefix sum of e in sorted (descending-u) order
    float pre = se;
#pragma unroll
    for (int off = 1; off <= 32; off <<= 1) {
      const float t = __shfl_up(pre, off, 64);
      if (lane >= off) pre += t;
    }
    const float excl = pre - se;
    const bool keep = (excl <= limit);  // first always kept (excl==0)
    const unsigned long long km = __ballot(keep);
    const int L = 63 - __builtin_clzll(km);
    const unsigned thr = ~(unsigned)__shfl((int)sk, L, 64);  // min kept value

    // Z over final kept set (u >= thr)
    float z2l = 0.f;
#pragma unroll
    for (int j = 0; j < 16; ++j) z2l += (u[qq][j] >= thr) ? e[j] : 0.f;
    const float Z2 = wsumf(z2l);
    const float wsc = fac[(b << 10) + q0 + qq] / Z2;

    // compact final kept (idx, weight) for PV; M <= 64 provably
    int M = 0;
#pragma unroll
    for (int j = 0; j < 16; ++j) {
      const bool f = (u[qq][j] >= thr);
      const unsigned long long mb = __ballot(f);
      if (f) {
        const int pos = M + (int)__popcll(mb & ltmask);
        if (pos < 64) {
          // key = pass*256 + lane*4 + jl, with j = pass*4 + jl
          ck[wid][pos] = ((j >> 2) << 8) + (lane << 2) + (j & 3);
          cv[wid][pos] = e[j] * wsc;
        }
      }
      M += (int)__popcll(mb);
    }
    if (M > 64) M = 64;

    // PV over surviving keys; lane = output dim d.
    // groups of 4 keys, ping-pong prefetched; a_t accumulates keys 4g+t
    // (ascending g) -> same per-accumulator order as before.
    float a0 = 0.f, a1 = 0.f, a2 = 0.f, a3 = 0.f;
    const int G = M >> 2;
    {
      float v0[4], v1[4];
      auto ldgrp = [&](float* vr, int base4) {
#pragma unroll
        for (int t = 0; t < 4; ++t)
          vr[t] = vb[((size_t)ck[wid][base4 + t] << 6) + lane];
      };
      auto fmagrp = [&](const float* vr, int base4) {
        a0 = fmaf(cv[wid][base4 + 0], vr[0], a0);
        a1 = fmaf(cv[wid][base4 + 1], vr[1], a1);
        a2 = fmaf(cv[wid][base4 + 2], vr[2], a2);
        a3 = fmaf(cv[wid][base4 + 3], vr[3], a3);
      };
      if (G > 0) {
        ldgrp(v0, 0);
        int g = 0;
        for (; g + 2 <= G; g += 2) {
          ldgrp(v1, (g + 1) << 2);
          fmagrp(v0, g << 2);
          if (g + 2 < G) ldgrp(v0, (g + 2) << 2);
          fmagrp(v1, (g + 1) << 2);
        }
        if (g < G) fmagrp(v0, g << 2);
      }
    }
    for (int i = G << 2; i < M; ++i)
      a0 = fmaf(cv[wid][i], vb[((size_t)ck[wid][i] << 6) + lane], a0);
    const float o = (a0 + a1) + (a2 + a3);

    ao[(((size_t)b << 10) + q0 + qq) * C_ + (h << 6) + lane] = o;
  }
}

extern "C" void kernel_launch(void* const* d_in, const int* in_sizes, int n_in,
                              void* d_out, int out_size, void* d_ws,
                              size_t ws_size, hipStream_t stream) {
  const float* x = (const float*)d_in[0];
  const float* wqkv = (const float*)d_in[1];
  const float* wout = (const float*)d_in[2];
  const float* bout = (const float*)d_in[3];
  const float* alpha = (const float*)d_in[4];
  const float* beta = (const float*)d_in[5];
  float* out = (float*)d_out;

  float* ws = (float*)d_ws;
  const size_t SZ = (size_t)B_ * H_ * N_ * HD_;  // 2M floats
  float* qw = ws;
  float* kt = ws + SZ;      // K stored transposed per head: [bh][d][n]
  float* vw = ws + 2 * SZ;
  float* ao = ws + 3 * SZ;
  float* fc = ws + 4 * SZ;

  factor_kernel<<<B_ * N_, 64, 0, stream>>>(x, alpha, beta, fc);
  gemm_qkv_kernel<<<dim3(3 * C_ / 128, B_ * N_ / 128), 256, 0, stream>>>(
      x, wqkv, qw, kt, vw);
  attn_kernel<<<(B_ * H_ * N_) / 16, 256, 0, stream>>>(qw, kt, vw, fc, ao);
  gemm_out_kernel<<<dim3(C_ / 128, B_ * N_ / 128), 256, 0, stream>>>(
      ao, wout, bout, out);
}

// Round 7
// 771.691 us; speedup vs baseline: 1.9407x; 1.9407x over previous
//
#include <hip/hip_runtime.h>

#define B_ 2
#define N_ 1024
#define C_ 1024
#define H_ 16
#define HD_ 64

// ---------- wave-wide (64-lane) helpers ----------
__device__ __forceinline__ float wsumf(float x) {
#pragma unroll
  for (int off = 32; off; off >>= 1) x += __shfl_xor(x, off, 64);
  return x;
}
// order-preserving float->uint map (total order matches float compare for non-NaN)
__device__ __forceinline__ unsigned orderu(float f) {
  unsigned b = __float_as_uint(f);
  return (b & 0x80000000u) ? ~b : (b | 0x80000000u);
}
__device__ __forceinline__ float iorderu(unsigned x) {
  unsigned b = (x & 0x80000000u) ? (x & 0x7FFFFFFFu) : ~x;
  return __uint_as_float(b);
}

// ---------- NKAT per-token factor ----------
__global__ __launch_bounds__(64) void factor_kernel(
    const float* __restrict__ x, const float* __restrict__ alpha_p,
    const float* __restrict__ beta_p, float* __restrict__ fac) {
  const int row = blockIdx.x;  // b*N + n
  const int lane = threadIdx.x;
  const float4* xr = (const float4*)(x + (size_t)row * C_);
  float s = 0.f, ss = 0.f;
#pragma unroll
  for (int j = 0; j < 4; ++j) {
    float4 v = xr[lane + 64 * j];
    s += v.x + v.y + v.z + v.w;
    ss += v.x * v.x + v.y * v.y + v.z * v.z + v.w * v.w;
  }
  s = wsumf(s);
  ss = wsumf(ss);
  const float mean = s * (1.f / 1024.f);
  const float var = ss * (1.f / 1024.f) - mean * mean;
  const float theta =
      alpha_p[0] * tanhf(mean) + beta_p[0] * (1.f / (1.f + __expf(-var)));
  if (lane == 0) fac[row] = 1.f + 0.45125f * theta;  // lc = 0.5*0.95^2
}

// ---------- shared f32 GEMM core: 128x128 tile, 256 thr, 8x8/thread, BK=8 ----------
__device__ __forceinline__ void gemm_core(const float* __restrict__ A,
                                          const float* __restrict__ Bm, int K,
                                          int N, int m0, int n0,
                                          float* __restrict__ a_lds,
                                          float* __restrict__ b_lds,
                                          float acc[8][8]) {
  const int tid = threadIdx.x;
  const int tx = tid & 15, ty = tid >> 4;
  const int r = tid >> 1, c4 = (tid & 1) << 2;     // A tile: 128 rows x 8 cols
  const int rb = tid >> 5, cb = (tid & 31) << 2;   // B tile: 8 rows x 128 cols
  float4 av = *(const float4*)(A + (size_t)(m0 + r) * K + c4);
  float4 bv = *(const float4*)(Bm + (size_t)rb * N + n0 + cb);
  for (int k0 = 0; k0 < K; k0 += 8) {
    __syncthreads();  // previous iteration's LDS reads done
    a_lds[(c4 + 0) * 128 + r] = av.x;  // store A transposed: [k][m]
    a_lds[(c4 + 1) * 128 + r] = av.y;
    a_lds[(c4 + 2) * 128 + r] = av.z;
    a_lds[(c4 + 3) * 128 + r] = av.w;
    *(float4*)(b_lds + rb * 128 + cb) = bv;
    __syncthreads();
    if (k0 + 8 < K) {  // prefetch next tile; latency hides under FMA phase
      av = *(const float4*)(A + (size_t)(m0 + r) * K + k0 + 8 + c4);
      bv = *(const float4*)(Bm + (size_t)(k0 + 8 + rb) * N + n0 + cb);
    }
#pragma unroll
    for (int kk = 0; kk < 8; ++kk) {
      const float4 a0 = *(const float4*)(a_lds + kk * 128 + ty * 8);
      const float4 a1 = *(const float4*)(a_lds + kk * 128 + ty * 8 + 4);
      const float4 b0 = *(const float4*)(b_lds + kk * 128 + tx * 8);
      const float4 b1 = *(const float4*)(b_lds + kk * 128 + tx * 8 + 4);
      const float af[8] = {a0.x, a0.y, a0.z, a0.w, a1.x, a1.y, a1.z, a1.w};
      const float bf[8] = {b0.x, b0.y, b0.z, b0.w, b1.x, b1.y, b1.z, b1.w};
#pragma unroll
      for (int i = 0; i < 8; ++i)
#pragma unroll
        for (int jj = 0; jj < 8; ++jj)
          acc[i][jj] = fmaf(af[i], bf[jj], acc[i][jj]);
    }
  }
}

// ---------- qkv = x @ w_qkv; Q,V in (B,H,N,HD); K TRANSPOSED: kt[bh][d][n] ----------
__global__ __launch_bounds__(256) void gemm_qkv_kernel(
    const float* __restrict__ x, const float* __restrict__ w,
    float* __restrict__ q, float* __restrict__ kt, float* __restrict__ v) {
  __shared__ __align__(16) float a_lds[8 * 128];
  __shared__ __align__(16) float b_lds[8 * 128];
  float acc[8][8];
#pragma unroll
  for (int i = 0; i < 8; ++i)
#pragma unroll
    for (int jj = 0; jj < 8; ++jj) acc[i][jj] = 0.f;
  const int m0 = blockIdx.y * 128, n0 = blockIdx.x * 128;
  gemm_core(x, w, C_, 3 * C_, m0, n0, a_lds, b_lds, acc);

  const int tx = threadIdx.x & 15, ty = threadIdx.x >> 4;
  const int j0 = n0 + tx * 8;           // 8 consecutive cols: same sel, same head
  const int sel = j0 >> 10;             // 0=q 1=k 2=v
  const int hh = (j0 >> 6) & 15;
  const int d0 = j0 & 63;
  const int bb = m0 >> 10;              // whole 128-row stripe in same batch
  const int nn0 = (m0 & 1023) + ty * 8; // rows nn0..nn0+7 consecutive

  if (sel == 1) {
    // K transposed: kt[((bb*16+hh)*64 + d)*1024 + n]; rows i are consecutive n
#pragma unroll
    for (int jj = 0; jj < 8; ++jj) {
      float* dst = kt + (((size_t)((bb << 4) + hh) * HD_ + d0 + jj) * N_ + nn0);
      *(float4*)dst = make_float4(acc[0][jj], acc[1][jj], acc[2][jj], acc[3][jj]);
      *(float4*)(dst + 4) =
          make_float4(acc[4][jj], acc[5][jj], acc[6][jj], acc[7][jj]);
    }
  } else {
    float* dstbuf = (sel == 0) ? q : v;
#pragma unroll
    for (int i = 0; i < 8; ++i) {
      float* dst = dstbuf + ((((size_t)(bb << 4)) + hh) * N_ + nn0 + i) * HD_ + d0;
      *(float4*)dst = make_float4(acc[i][0], acc[i][1], acc[i][2], acc[i][3]);
      *(float4*)(dst + 4) =
          make_float4(acc[i][4], acc[i][5], acc[i][6], acc[i][7]);
    }
  }
}

// ---------- out = attn_out @ w_out + b_out ----------
__global__ __launch_bounds__(256) void gemm_out_kernel(
    const float* __restrict__ a, const float* __restrict__ w,
    const float* __restrict__ bias, float* __restrict__ out) {
  __shared__ __align__(16) float a_lds[8 * 128];
  __shared__ __align__(16) float b_lds[8 * 128];
  float acc[8][8];
#pragma unroll
  for (int i = 0; i < 8; ++i)
#pragma unroll
    for (int jj = 0; jj < 8; ++jj) acc[i][jj] = 0.f;
  const int m0 = blockIdx.y * 128, n0 = blockIdx.x * 128;
  gemm_core(a, w, C_, C_, m0, n0, a_lds, b_lds, acc);

  const int tx = threadIdx.x & 15, ty = threadIdx.x >> 4;
  const int j0 = n0 + tx * 8;
  const float4 bs0 = *(const float4*)(bias + j0);
  const float4 bs1 = *(const float4*)(bias + j0 + 4);
#pragma unroll
  for (int i = 0; i < 8; ++i) {
    const int mm = m0 + ty * 8 + i;
    float* dst = out + (size_t)mm * C_ + j0;
    *(float4*)dst = make_float4(acc[i][0] + bs0.x, acc[i][1] + bs0.y,
                                acc[i][2] + bs0.z, acc[i][3] + bs0.w);
    *(float4*)(dst + 4) = make_float4(acc[i][4] + bs1.x, acc[i][5] + bs1.y,
                                      acc[i][6] + bs1.z, acc[i][7] + bs1.w);
  }
}

// ---------- attention: 4 waves/block, 4 queries/wave; coalesced K^T scores ----------
// key = pass*256 + lane*4 + jl ; u[q][pass*4+jl] is the selection state.
// Selection pipeline (compact, bitonic sort, prefix scan, threshold) runs
// 4-queries-in-lockstep for 4-way ILP on the dependent cross-lane chains.
__global__ __launch_bounds__(256) void attn_kernel(
    const float* __restrict__ qw, const float* __restrict__ kt,
    const float* __restrict__ vw, const float* __restrict__ fac,
    float* __restrict__ ao) {
  const int lane = threadIdx.x & 63;
  const int wid = threadIdx.x >> 6;
  const int qblk = blockIdx.x * 16;      // 16 queries per block, same (b,h)
  const int bh = qblk >> 10;
  const int b = bh >> 4, h = bh & 15;
  const int q0 = (qblk & (N_ - 1)) + wid * 4;  // first query of this wave

  __shared__ __align__(16) float q_ldsT[4][HD_][4];  // [wave][d][query]
  __shared__ unsigned su[4][4][64];  // [wave][query][pos]
  __shared__ float sv[4][4][64];
  __shared__ int ck[4][64];
  __shared__ float cv[4][64];

  // load this wave's 4 query vectors, store transposed [d][q]; wave-private,
  // DS ops in-order within a wave -> no barrier needed
  {
    const int qq = lane >> 4, dp = (lane & 15) << 2;
    const float4 v =
        *(const float4*)(qw + ((size_t)bh * N_ + q0 + qq) * HD_ + dp);
    q_ldsT[wid][dp + 0][qq] = v.x;
    q_ldsT[wid][dp + 1][qq] = v.y;
    q_ldsT[wid][dp + 2][qq] = v.z;
    q_ldsT[wid][dp + 3][qq] = v.w;
  }

  const float* ktb = kt + ((size_t)bh * HD_ * N_);  // [d][n]
  const unsigned long long ltmask = (1ull << lane) - 1ull;
  unsigned u[4][16];  // [query][pass*4+jl]

  // ---- score phase: fully-coalesced K^T streaming (round-5 form) ----
  for (int pass = 0; pass < 4; ++pass) {
    float acc[4][4];  // [jl][query]
#pragma unroll
    for (int a = 0; a < 4; ++a)
#pragma unroll
      for (int c = 0; c < 4; ++c) acc[a][c] = 0.f;
    const float* kp = ktb + (pass << 8) + (lane << 2);
#pragma unroll 4
    for (int d = 0; d < HD_; ++d) {
      const float4 kv = *(const float4*)(kp + (size_t)d * N_);
      const float4 qv = *(const float4*)(&q_ldsT[wid][d][0]);  // broadcast
      acc[0][0] = fmaf(kv.x, qv.x, acc[0][0]);
      acc[0][1] = fmaf(kv.x, qv.y, acc[0][1]);
      acc[0][2] = fmaf(kv.x, qv.z, acc[0][2]);
      acc[0][3] = fmaf(kv.x, qv.w, acc[0][3]);
      acc[1][0] = fmaf(kv.y, qv.x, acc[1][0]);
      acc[1][1] = fmaf(kv.y, qv.y, acc[1][1]);
      acc[1][2] = fmaf(kv.y, qv.z, acc[1][2]);
      acc[1][3] = fmaf(kv.y, qv.w, acc[1][3]);
      acc[2][0] = fmaf(kv.z, qv.x, acc[2][0]);
      acc[2][1] = fmaf(kv.z, qv.y, acc[2][1]);
      acc[2][2] = fmaf(kv.z, qv.z, acc[2][2]);
      acc[2][3] = fmaf(kv.z, qv.w, acc[2][3]);
      acc[3][0] = fmaf(kv.w, qv.x, acc[3][0]);
      acc[3][1] = fmaf(kv.w, qv.y, acc[3][1]);
      acc[3][2] = fmaf(kv.w, qv.z, acc[3][2]);
      acc[3][3] = fmaf(kv.w, qv.w, acc[3][3]);
    }
#pragma unroll
    for (int jl = 0; jl < 4; ++jl)
#pragma unroll
      for (int q = 0; q < 4; ++q)
        u[q][(pass << 2) + jl] = orderu((acc[jl][q] * 0.125f) / 0.8f);
  }

  // ---- batched wave-max over 4 queries (integer max == float max) ----
  unsigned mu[4];
#pragma unroll
  for (int q = 0; q < 4; ++q) {
    unsigned mq = u[q][0];
#pragma unroll
    for (int j = 1; j < 16; ++j) mq = max(mq, u[q][j]);
    mu[q] = mq;
  }
#pragma unroll
  for (int off = 32; off; off >>= 1) {
#pragma unroll
    for (int q = 0; q < 4; ++q)
      mu[q] = max(mu[q], (unsigned)__shfl_xor((int)mu[q], off, 64));
  }

  // ---- batched top-k binary searches (4 independent chains, lockstep) ----
  unsigned lo[4], hi[4];
#pragma unroll
  for (int q = 0; q < 4; ++q) { lo[q] = 0u; hi[q] = mu[q]; }
  while ((lo[0] < hi[0]) | (lo[1] < hi[1]) | (lo[2] < hi[2]) |
         (lo[3] < hi[3])) {
#pragma unroll
    for (int q = 0; q < 4; ++q) {
      if (lo[q] < hi[q]) {  // wave-uniform condition
        const unsigned mid = lo[q] + ((hi[q] - lo[q]) >> 1) + 1u;
        int c = 0;
#pragma unroll
        for (int j = 0; j < 16; ++j)
          c += (int)__popcll(__ballot(u[q][j] >= mid));
        if (c >= 64) lo[q] = mid; else hi[q] = mid - 1u;
      }
    }
  }

  // ---- batched: Z (same per-(q,j) order/gating as before) ----
  float m4[4], zl[4];
#pragma unroll
  for (int q = 0; q < 4; ++q) {
    m4[q] = iorderu(mu[q]);
    float z = 0.f;
#pragma unroll
    for (int j = 0; j < 16; ++j)
      z += (u[q][j] >= lo[q]) ? expf(iorderu(u[q][j]) - m4[q]) : 0.f;
    zl[q] = z;
  }
#pragma unroll
  for (int off = 32; off; off >>= 1)
#pragma unroll
    for (int q = 0; q < 4; ++q) zl[q] += __shfl_xor(zl[q], off, 64);
  float limitq[4];
#pragma unroll
  for (int q = 0; q < 4; ++q) limitq[q] = 0.9f * zl[q];  // TOP_P * Z

  // ---- batched compact of survivors (u>=kth) into su/sv, one per lane ----
  {
    int basep[4] = {0, 0, 0, 0};
#pragma unroll
    for (int j = 0; j < 16; ++j) {
#pragma unroll
      for (int q = 0; q < 4; ++q) {
        const bool f = (u[q][j] >= lo[q]);
        const unsigned long long mb = __ballot(f);
        if (f) {
          const int pos = basep[q] + (int)__popcll(mb & ltmask);
          if (pos < 64) {
            su[wid][q][pos] = u[q][j];
            sv[wid][q][pos] = expf(iorderu(u[q][j]) - m4[q]);
          }
        }
        basep[q] += (int)__popcll(mb);
      }
    }
  }

  // ---- batched bitonic sort (4 independent networks in lockstep) ----
  unsigned skq[4];
  float seq[4];
#pragma unroll
  for (int q = 0; q < 4; ++q) {
    skq[q] = ~su[wid][q][lane];  // ascending by ~u == descending by u
    seq[q] = sv[wid][q][lane];
  }
#pragma unroll
  for (int k = 2; k <= 64; k <<= 1) {
#pragma unroll
    for (int j = k >> 1; j; j >>= 1) {
      const bool takeMin = (((lane & j) == 0) == ((lane & k) == 0));
#pragma unroll
      for (int q = 0; q < 4; ++q) {
        const unsigned pk = (unsigned)__shfl_xor((int)skq[q], j, 64);
        const float pe = __shfl_xor(seq[q], j, 64);
        const bool sw = takeMin ? (pk < skq[q]) : (pk > skq[q]);
        if (sw) { skq[q] = pk; seq[q] = pe; }
      }
    }
  }

  // ---- batched inclusive prefix scan of e in sorted order ----
  float preq[4];
#pragma unroll
  for (int q = 0; q < 4; ++q) preq[q] = seq[q];
#pragma unroll
  for (int off = 1; off <= 32; off <<= 1) {
#pragma unroll
    for (int q = 0; q < 4; ++q) {
      const float t = __shfl_up(preq[q], off, 64);
      if (lane >= off) preq[q] += t;
    }
  }

  // ---- batched threshold extraction ----
  unsigned thrq[4];
#pragma unroll
  for (int q = 0; q < 4; ++q) {
    const bool keep = (preq[q] - seq[q]) <= limitq[q];  // first always kept
    const unsigned long long km = __ballot(keep);
    const int L = 63 - __builtin_clzll(km);
    thrq[q] = ~(unsigned)__shfl((int)skq[q], L, 64);  // min kept value
  }

  // ---- per-query: Z2 + weight compact + PV (round-5 form) ----
  const float* vb = vw + ((size_t)bh << 16);
#pragma unroll
  for (int qq = 0; qq < 4; ++qq) {
    const unsigned kthu = lo[qq];
    const unsigned thr = thrq[qq];
    const float m = m4[qq];

    float e[16];
#pragma unroll
    for (int j = 0; j < 16; ++j)
      e[j] = (u[qq][j] >= kthu) ? expf(iorderu(u[qq][j]) - m) : 0.f;

    // Z over final kept set (u >= thr); same order as round 5
    float z2l = 0.f;
#pragma unroll
    for (int j = 0; j < 16; ++j) z2l += (u[qq][j] >= thr) ? e[j] : 0.f;
    const float Z2 = wsumf(z2l);
    const float wsc = fac[(b << 10) + q0 + qq] / Z2;

    // compact final kept (idx, weight) for PV; M <= 64 provably
    int M = 0;
#pragma unroll
    for (int j = 0; j < 16; ++j) {
      const bool f = (u[qq][j] >= thr);
      const unsigned long long mb = __ballot(f);
      if (f) {
        const int pos = M + (int)__popcll(mb & ltmask);
        if (pos < 64) {
          // key = pass*256 + lane*4 + jl, with j = pass*4 + jl
          ck[wid][pos] = ((j >> 2) << 8) + (lane << 2) + (j & 3);
          cv[wid][pos] = e[j] * wsc;
        }
      }
      M += (int)__popcll(mb);
    }
    if (M > 64) M = 64;

    // PV over surviving keys; lane = output dim d
    float a0 = 0.f, a1 = 0.f, a2 = 0.f, a3 = 0.f;
    int i = 0;
    for (; i + 4 <= M; i += 4) {
      const int k0 = ck[wid][i], k1 = ck[wid][i + 1];
      const int k2 = ck[wid][i + 2], k3 = ck[wid][i + 3];
      const float c0 = cv[wid][i], c1 = cv[wid][i + 1];
      const float c2 = cv[wid][i + 2], c3 = cv[wid][i + 3];
      a0 = fmaf(c0, vb[((size_t)k0 << 6) + lane], a0);
      a1 = fmaf(c1, vb[((size_t)k1 << 6) + lane], a1);
      a2 = fmaf(c2, vb[((size_t)k2 << 6) + lane], a2);
      a3 = fmaf(c3, vb[((size_t)k3 << 6) + lane], a3);
    }
    for (; i < M; ++i)
      a0 = fmaf(cv[wid][i], vb[((size_t)ck[wid][i] << 6) + lane], a0);
    const float o = (a0 + a1) + (a2 + a3);

    ao[(((size_t)b << 10) + q0 + qq) * C_ + (h << 6) + lane] = o;
  }
}

extern "C" void kernel_launch(void* const* d_in, const int* in_sizes, int n_in,
                              void* d_out, int out_size, void* d_ws,
                              size_t ws_size, hipStream_t stream) {
  const float* x = (const float*)d_in[0];
  const float* wqkv = (const float*)d_in[1];
  const float* wout = (const float*)d_in[2];
  const float* bout = (const float*)d_in[3];
  const float* alpha = (const float*)d_in[4];
  const float* beta = (const float*)d_in[5];
  float* out = (float*)d_out;

  float* ws = (float*)d_ws;
  const size_t SZ = (size_t)B_ * H_ * N_ * HD_;  // 2M floats
  float* qw = ws;
  float* kt = ws + SZ;      // K stored transposed per head: [bh][d][n]
  float* vw = ws + 2 * SZ;
  float* ao = ws + 3 * SZ;
  float* fc = ws + 4 * SZ;

  factor_kernel<<<B_ * N_, 64, 0, stream>>>(x, alpha, beta, fc);
  gemm_qkv_kernel<<<dim3(3 * C_ / 128, B_ * N_ / 128), 256, 0, stream>>>(
      x, wqkv, qw, kt, vw);
  attn_kernel<<<(B_ * H_ * N_) / 16, 256, 0, stream>>>(qw, kt, vw, fc, ao);
  gemm_out_kernel<<<dim3(C_ / 128, B_ * N_ / 128), 256, 0, stream>>>(
      ao, wout, bout, out);
}

// Round 8
// 534.804 us; speedup vs baseline: 2.8004x; 1.4429x over previous
//
#include <hip/hip_runtime.h>

#define B_ 2
#define N_ 1024
#define C_ 1024
#define H_ 16
#define HD_ 64

// ---------- wave-wide (64-lane) helpers ----------
__device__ __forceinline__ float wsumf(float x) {
#pragma unroll
  for (int off = 32; off; off >>= 1) x += __shfl_xor(x, off, 64);
  return x;
}
// order-preserving float->uint map (total order matches float compare for non-NaN)
__device__ __forceinline__ unsigned orderu(float f) {
  unsigned b = __float_as_uint(f);
  return (b & 0x80000000u) ? ~b : (b | 0x80000000u);
}
__device__ __forceinline__ float iorderu(unsigned x) {
  unsigned b = (x & 0x80000000u) ? (x & 0x7FFFFFFFu) : ~x;
  return __uint_as_float(b);
}

// ---------- NKAT per-token factor ----------
__global__ __launch_bounds__(64) void factor_kernel(
    const float* __restrict__ x, const float* __restrict__ alpha_p,
    const float* __restrict__ beta_p, float* __restrict__ fac) {
  const int row = blockIdx.x;  // b*N + n
  const int lane = threadIdx.x;
  const float4* xr = (const float4*)(x + (size_t)row * C_);
  float s = 0.f, ss = 0.f;
#pragma unroll
  for (int j = 0; j < 4; ++j) {
    float4 v = xr[lane + 64 * j];
    s += v.x + v.y + v.z + v.w;
    ss += v.x * v.x + v.y * v.y + v.z * v.z + v.w * v.w;
  }
  s = wsumf(s);
  ss = wsumf(ss);
  const float mean = s * (1.f / 1024.f);
  const float var = ss * (1.f / 1024.f) - mean * mean;
  const float theta =
      alpha_p[0] * tanhf(mean) + beta_p[0] * (1.f / (1.f + __expf(-var)));
  if (lane == 0) fac[row] = 1.f + 0.45125f * theta;  // lc = 0.5*0.95^2
}

// ---------- shared f32 GEMM core: 128x128 tile, 256 thr, 8x8/thread, BK=8 ----------
__device__ __forceinline__ void gemm_core(const float* __restrict__ A,
                                          const float* __restrict__ Bm, int K,
                                          int N, int m0, int n0,
                                          float* __restrict__ a_lds,
                                          float* __restrict__ b_lds,
                                          float acc[8][8]) {
  const int tid = threadIdx.x;
  const int tx = tid & 15, ty = tid >> 4;
  const int r = tid >> 1, c4 = (tid & 1) << 2;     // A tile: 128 rows x 8 cols
  const int rb = tid >> 5, cb = (tid & 31) << 2;   // B tile: 8 rows x 128 cols
  float4 av = *(const float4*)(A + (size_t)(m0 + r) * K + c4);
  float4 bv = *(const float4*)(Bm + (size_t)rb * N + n0 + cb);
  for (int k0 = 0; k0 < K; k0 += 8) {
    __syncthreads();  // previous iteration's LDS reads done
    a_lds[(c4 + 0) * 128 + r] = av.x;  // store A transposed: [k][m]
    a_lds[(c4 + 1) * 128 + r] = av.y;
    a_lds[(c4 + 2) * 128 + r] = av.z;
    a_lds[(c4 + 3) * 128 + r] = av.w;
    *(float4*)(b_lds + rb * 128 + cb) = bv;
    __syncthreads();
    if (k0 + 8 < K) {  // prefetch next tile; latency hides under FMA phase
      av = *(const float4*)(A + (size_t)(m0 + r) * K + k0 + 8 + c4);
      bv = *(const float4*)(Bm + (size_t)(k0 + 8 + rb) * N + n0 + cb);
    }
#pragma unroll
    for (int kk = 0; kk < 8; ++kk) {
      const float4 a0 = *(const float4*)(a_lds + kk * 128 + ty * 8);
      const float4 a1 = *(const float4*)(a_lds + kk * 128 + ty * 8 + 4);
      const float4 b0 = *(const float4*)(b_lds + kk * 128 + tx * 8);
      const float4 b1 = *(const float4*)(b_lds + kk * 128 + tx * 8 + 4);
      const float af[8] = {a0.x, a0.y, a0.z, a0.w, a1.x, a1.y, a1.z, a1.w};
      const float bf[8] = {b0.x, b0.y, b0.z, b0.w, b1.x, b1.y, b1.z, b1.w};
#pragma unroll
      for (int i = 0; i < 8; ++i)
#pragma unroll
        for (int jj = 0; jj < 8; ++jj)
          acc[i][jj] = fmaf(af[i], bf[jj], acc[i][jj]);
    }
  }
}

// ---------- qkv = x @ w_qkv; Q,V in (B,H,N,HD); K TRANSPOSED: kt[bh][d][n] ----------
__global__ __launch_bounds__(256) void gemm_qkv_kernel(
    const float* __restrict__ x, const float* __restrict__ w,
    float* __restrict__ q, float* __restrict__ kt, float* __restrict__ v) {
  __shared__ __align__(16) float a_lds[8 * 128];
  __shared__ __align__(16) float b_lds[8 * 128];
  float acc[8][8];
#pragma unroll
  for (int i = 0; i < 8; ++i)
#pragma unroll
    for (int jj = 0; jj < 8; ++jj) acc[i][jj] = 0.f;
  const int m0 = blockIdx.y * 128, n0 = blockIdx.x * 128;
  gemm_core(x, w, C_, 3 * C_, m0, n0, a_lds, b_lds, acc);

  const int tx = threadIdx.x & 15, ty = threadIdx.x >> 4;
  const int j0 = n0 + tx * 8;           // 8 consecutive cols: same sel, same head
  const int sel = j0 >> 10;             // 0=q 1=k 2=v
  const int hh = (j0 >> 6) & 15;
  const int d0 = j0 & 63;
  const int bb = m0 >> 10;              // whole 128-row stripe in same batch
  const int nn0 = (m0 & 1023) + ty * 8; // rows nn0..nn0+7 consecutive

  if (sel == 1) {
    // K transposed: kt[((bb*16+hh)*64 + d)*1024 + n]; rows i are consecutive n
#pragma unroll
    for (int jj = 0; jj < 8; ++jj) {
      float* dst = kt + (((size_t)((bb << 4) + hh) * HD_ + d0 + jj) * N_ + nn0);
      *(float4*)dst = make_float4(acc[0][jj], acc[1][jj], acc[2][jj], acc[3][jj]);
      *(float4*)(dst + 4) =
          make_float4(acc[4][jj], acc[5][jj], acc[6][jj], acc[7][jj]);
    }
  } else {
    float* dstbuf = (sel == 0) ? q : v;
#pragma unroll
    for (int i = 0; i < 8; ++i) {
      float* dst = dstbuf + ((((size_t)(bb << 4)) + hh) * N_ + nn0 + i) * HD_ + d0;
      *(float4*)dst = make_float4(acc[i][0], acc[i][1], acc[i][2], acc[i][3]);
      *(float4*)(dst + 4) =
          make_float4(acc[i][4], acc[i][5], acc[i][6], acc[i][7]);
    }
  }
}

// ---------- out = attn_out @ w_out + b_out ----------
__global__ __launch_bounds__(256) void gemm_out_kernel(
    const float* __restrict__ a, const float* __restrict__ w,
    const float* __restrict__ bias, float* __restrict__ out) {
  __shared__ __align__(16) float a_lds[8 * 128];
  __shared__ __align__(16) float b_lds[8 * 128];
  float acc[8][8];
#pragma unroll
  for (int i = 0; i < 8; ++i)
#pragma unroll
    for (int jj = 0; jj < 8; ++jj) acc[i][jj] = 0.f;
  const int m0 = blockIdx.y * 128, n0 = blockIdx.x * 128;
  gemm_core(a, w, C_, C_, m0, n0, a_lds, b_lds, acc);

  const int tx = threadIdx.x & 15, ty = threadIdx.x >> 4;
  const int j0 = n0 + tx * 8;
  const float4 bs0 = *(const float4*)(bias + j0);
  const float4 bs1 = *(const float4*)(bias + j0 + 4);
#pragma unroll
  for (int i = 0; i < 8; ++i) {
    const int mm = m0 + ty * 8 + i;
    float* dst = out + (size_t)mm * C_ + j0;
    *(float4*)dst = make_float4(acc[i][0] + bs0.x, acc[i][1] + bs0.y,
                                acc[i][2] + bs0.z, acc[i][3] + bs0.w);
    *(float4*)(dst + 4) = make_float4(acc[i][4] + bs1.x, acc[i][5] + bs1.y,
                                      acc[i][6] + bs1.z, acc[i][7] + bs1.w);
  }
}

// ---------- attention: 4 waves/block, 4 queries/wave; coalesced K^T scores ----------
// Round-5 structure (VGPR-light, occupancy-first). Changes vs round 5:
//  * __expf instead of libm expf (selection driven by u bits -> no flip risk)
//  * top-k search bounds tightened to [min-lane-max, wave-max] (kth provably
//    inside: the 64 lane-maxima are all >= min-lane-max)
__global__ __launch_bounds__(256) void attn_kernel(
    const float* __restrict__ qw, const float* __restrict__ kt,
    const float* __restrict__ vw, const float* __restrict__ fac,
    float* __restrict__ ao) {
  const int lane = threadIdx.x & 63;
  const int wid = threadIdx.x >> 6;
  const int qblk = blockIdx.x * 16;      // 16 queries per block, same (b,h)
  const int bh = qblk >> 10;
  const int b = bh >> 4, h = bh & 15;
  const int q0 = (qblk & (N_ - 1)) + wid * 4;  // first query of this wave

  __shared__ __align__(16) float q_ldsT[4][HD_][4];  // [wave][d][query]
  __shared__ unsigned su[4][64];
  __shared__ float sv[4][64];
  __shared__ int ck[4][64];
  __shared__ float cv[4][64];

  // load this wave's 4 query vectors, store transposed [d][q]; wave-private,
  // DS ops in-order within a wave -> no barrier needed
  {
    const int qq = lane >> 4, dp = (lane & 15) << 2;
    const float4 v =
        *(const float4*)(qw + ((size_t)bh * N_ + q0 + qq) * HD_ + dp);
    q_ldsT[wid][dp + 0][qq] = v.x;
    q_ldsT[wid][dp + 1][qq] = v.y;
    q_ldsT[wid][dp + 2][qq] = v.z;
    q_ldsT[wid][dp + 3][qq] = v.w;
  }

  const float* ktb = kt + ((size_t)bh * HD_ * N_);  // [d][n]
  const unsigned long long ltmask = (1ull << lane) - 1ull;
  unsigned u[4][16];  // [query][pass*4+jl]

  // ---- score phase: fully-coalesced K^T streaming (round-5 form) ----
  for (int pass = 0; pass < 4; ++pass) {
    float acc[4][4];  // [jl][query]
#pragma unroll
    for (int a = 0; a < 4; ++a)
#pragma unroll
      for (int c = 0; c < 4; ++c) acc[a][c] = 0.f;
    const float* kp = ktb + (pass << 8) + (lane << 2);
#pragma unroll 4
    for (int d = 0; d < HD_; ++d) {
      const float4 kv = *(const float4*)(kp + (size_t)d * N_);
      const float4 qv = *(const float4*)(&q_ldsT[wid][d][0]);  // broadcast
      acc[0][0] = fmaf(kv.x, qv.x, acc[0][0]);
      acc[0][1] = fmaf(kv.x, qv.y, acc[0][1]);
      acc[0][2] = fmaf(kv.x, qv.z, acc[0][2]);
      acc[0][3] = fmaf(kv.x, qv.w, acc[0][3]);
      acc[1][0] = fmaf(kv.y, qv.x, acc[1][0]);
      acc[1][1] = fmaf(kv.y, qv.y, acc[1][1]);
      acc[1][2] = fmaf(kv.y, qv.z, acc[1][2]);
      acc[1][3] = fmaf(kv.y, qv.w, acc[1][3]);
      acc[2][0] = fmaf(kv.z, qv.x, acc[2][0]);
      acc[2][1] = fmaf(kv.z, qv.y, acc[2][1]);
      acc[2][2] = fmaf(kv.z, qv.z, acc[2][2]);
      acc[2][3] = fmaf(kv.z, qv.w, acc[2][3]);
      acc[3][0] = fmaf(kv.w, qv.x, acc[3][0]);
      acc[3][1] = fmaf(kv.w, qv.y, acc[3][1]);
      acc[3][2] = fmaf(kv.w, qv.z, acc[3][2]);
      acc[3][3] = fmaf(kv.w, qv.w, acc[3][3]);
    }
#pragma unroll
    for (int jl = 0; jl < 4; ++jl)
#pragma unroll
      for (int q = 0; q < 4; ++q)
        u[q][(pass << 2) + jl] = orderu((acc[jl][q] * 0.125f) / 0.8f);
  }

  // ---- batched wave-max + min-lane-max over 4 queries ----
  unsigned mu[4], l0[4];
#pragma unroll
  for (int q = 0; q < 4; ++q) {
    unsigned mq = u[q][0];
#pragma unroll
    for (int j = 1; j < 16; ++j) mq = max(mq, u[q][j]);
    mu[q] = mq;   // lane-local max -> wave max below
    l0[q] = mq;   // lane-local max -> wave MIN below (lower bound for kth)
  }
#pragma unroll
  for (int off = 32; off; off >>= 1) {
#pragma unroll
    for (int q = 0; q < 4; ++q) {
      mu[q] = max(mu[q], (unsigned)__shfl_xor((int)mu[q], off, 64));
      l0[q] = min(l0[q], (unsigned)__shfl_xor((int)l0[q], off, 64));
    }
  }

  // ---- batched top-k binary searches (4 independent chains, lockstep) ----
  // invariant: count(u >= lo) >= 64 (holds at lo=l0: 64 lane-maxima >= l0)
  unsigned lo[4], hi[4];
#pragma unroll
  for (int q = 0; q < 4; ++q) { lo[q] = l0[q]; hi[q] = mu[q]; }
  while ((lo[0] < hi[0]) | (lo[1] < hi[1]) | (lo[2] < hi[2]) |
         (lo[3] < hi[3])) {
#pragma unroll
    for (int q = 0; q < 4; ++q) {
      if (lo[q] < hi[q]) {  // wave-uniform condition
        const unsigned mid = lo[q] + ((hi[q] - lo[q]) >> 1) + 1u;
        int c = 0;
#pragma unroll
        for (int j = 0; j < 16; ++j)
          c += (int)__popcll(__ballot(u[q][j] >= mid));
        if (c >= 64) lo[q] = mid; else hi[q] = mid - 1u;
      }
    }
  }

  // ---- per-query: top-p + softmax + PV ----
  const float* vb = vw + ((size_t)bh << 16);
#pragma unroll
  for (int qq = 0; qq < 4; ++qq) {
    const unsigned kthu = lo[qq];
    const float m = iorderu(mu[qq]);

    // exp over kept set (others exactly 0 = exp(NEG-m) underflow)
    float e[16];
    float zl = 0.f;
#pragma unroll
    for (int j = 0; j < 16; ++j) {
      const float ej =
          (u[qq][j] >= kthu) ? __expf(iorderu(u[qq][j]) - m) : 0.f;
      e[j] = ej;
      zl += ej;
    }
    const float Z = wsumf(zl);
    const float limit = 0.9f * Z;  // TOP_P * Z

    // compact survivors (u>=kth; count >= 64 always, so slots 0..63 all fill)
    int base = 0;
#pragma unroll
    for (int j = 0; j < 16; ++j) {
      const bool f = (u[qq][j] >= kthu);
      const unsigned long long mb = __ballot(f);
      if (f) {
        const int pos = base + (int)__popcll(mb & ltmask);
        if (pos < 64) {
          su[wid][pos] = u[qq][j];
          sv[wid][pos] = e[j];
        }
      }
      base += (int)__popcll(mb);
    }

    // bitonic sort across 64 lanes, ascending by ~u (= descending by u)
    unsigned sk = ~su[wid][lane];
    float se = sv[wid][lane];
#pragma unroll
    for (int k = 2; k <= 64; k <<= 1) {
#pragma unroll
      for (int j = k >> 1; j; j >>= 1) {
        const unsigned pk = (unsigned)__shfl_xor((int)sk, j, 64);
        const float pe = __shfl_xor(se, j, 64);
        const bool takeMin = (((lane & j) == 0) == ((lane & k) == 0));
        const bool sw = takeMin ? (pk < sk) : (pk > sk);
        if (sw) { sk = pk; se = pe; }
      }
    }

    // inclusive prefix sum of e in sorted (descending-u) order
    float pre = se;
#pragma unroll
    for (int off = 1; off <= 32; off <<= 1) {
      const float t = __shfl_up(pre, off, 64);
      if (lane >= off) pre += t;
    }
    const float excl = pre - se;
    const bool keep = (excl <= limit);  // first always kept (excl==0)
    const unsigned long long km = __ballot(keep);
    const int L = 63 - __builtin_clzll(km);
    const unsigned thr = ~(unsigned)__shfl((int)sk, L, 64);  // min kept value

    // Z over final kept set (u >= thr)
    float z2l = 0.f;
#pragma unroll
    for (int j = 0; j < 16; ++j) z2l += (u[qq][j] >= thr) ? e[j] : 0.f;
    const float Z2 = wsumf(z2l);
    const float wsc = fac[(b << 10) + q0 + qq] / Z2;

    // compact final kept (idx, weight) for PV; M <= 64 provably
    int M = 0;
#pragma unroll
    for (int j = 0; j < 16; ++j) {
      const bool f = (u[qq][j] >= thr);
      const unsigned long long mb = __ballot(f);
      if (f) {
        const int pos = M + (int)__popcll(mb & ltmask);
        if (pos < 64) {
          // key = pass*256 + lane*4 + jl, with j = pass*4 + jl
          ck[wid][pos] = ((j >> 2) << 8) + (lane << 2) + (j & 3);
          cv[wid][pos] = e[j] * wsc;
        }
      }
      M += (int)__popcll(mb);
    }
    if (M > 64) M = 64;

    // PV over surviving keys; lane = output dim d
    float a0 = 0.f, a1 = 0.f, a2 = 0.f, a3 = 0.f;
    int i = 0;
    for (; i + 4 <= M; i += 4) {
      const int k0 = ck[wid][i], k1 = ck[wid][i + 1];
      const int k2 = ck[wid][i + 2], k3 = ck[wid][i + 3];
      const float c0 = cv[wid][i], c1 = cv[wid][i + 1];
      const float c2 = cv[wid][i + 2], c3 = cv[wid][i + 3];
      a0 = fmaf(c0, vb[((size_t)k0 << 6) + lane], a0);
      a1 = fmaf(c1, vb[((size_t)k1 << 6) + lane], a1);
      a2 = fmaf(c2, vb[((size_t)k2 << 6) + lane], a2);
      a3 = fmaf(c3, vb[((size_t)k3 << 6) + lane], a3);
    }
    for (; i < M; ++i)
      a0 = fmaf(cv[wid][i], vb[((size_t)ck[wid][i] << 6) + lane], a0);
    const float o = (a0 + a1) + (a2 + a3);

    ao[(((size_t)b << 10) + q0 + qq) * C_ + (h << 6) + lane] = o;
  }
}

extern "C" void kernel_launch(void* const* d_in, const int* in_sizes, int n_in,
                              void* d_out, int out_size, void* d_ws,
                              size_t ws_size, hipStream_t stream) {
  const float* x = (const float*)d_in[0];
  const float* wqkv = (const float*)d_in[1];
  const float* wout = (const float*)d_in[2];
  const float* bout = (const float*)d_in[3];
  const float* alpha = (const float*)d_in[4];
  const float* beta = (const float*)d_in[5];
  float* out = (float*)d_out;

  float* ws = (float*)d_ws;
  const size_t SZ = (size_t)B_ * H_ * N_ * HD_;  // 2M floats
  float* qw = ws;
  float* kt = ws + SZ;      // K stored transposed per head: [bh][d][n]
  float* vw = ws + 2 * SZ;
  float* ao = ws + 3 * SZ;
  float* fc = ws + 4 * SZ;

  factor_kernel<<<B_ * N_, 64, 0, stream>>>(x, alpha, beta, fc);
  gemm_qkv_kernel<<<dim3(3 * C_ / 128, B_ * N_ / 128), 256, 0, stream>>>(
      x, wqkv, qw, kt, vw);
  attn_kernel<<<(B_ * H_ * N_) / 16, 256, 0, stream>>>(qw, kt, vw, fc, ao);
  gemm_out_kernel<<<dim3(C_ / 128, B_ * N_ / 128), 256, 0, stream>>>(
      ao, wout, bout, out);
}

// Round 10
// 447.320 us; speedup vs baseline: 3.3480x; 1.1956x over previous
//
#include <hip/hip_runtime.h>

#define B_ 2
#define N_ 1024
#define C_ 1024
#define H_ 16
#define HD_ 64
#define KPAD 36   // u32 per LDS row (144B stride): 16B-aligned b128 reads
#define KPADL 40  // u16 per LDS row (80B stride): 16B-aligned b128 reads

typedef short short8 __attribute__((ext_vector_type(8)));
typedef float f32x4 __attribute__((ext_vector_type(4)));

union U16 {
  uint4 q;
  unsigned u[4];
  short8 s;
};

// ---------- wave-wide (64-lane) helpers ----------
__device__ __forceinline__ float wsumf(float x) {
#pragma unroll
  for (int off = 32; off; off >>= 1) x += __shfl_xor(x, off, 64);
  return x;
}
__device__ __forceinline__ unsigned orderu(float f) {
  unsigned b = __float_as_uint(f);
  return (b & 0x80000000u) ? ~b : (b | 0x80000000u);
}
__device__ __forceinline__ float iorderu(unsigned x) {
  unsigned b = (x & 0x80000000u) ? (x & 0x7FFFFFFFu) : ~x;
  return __uint_as_float(b);
}

// 2-term split f32 -> packed u32: hi bf16 in low16, lo bf16 in high16 (RTNE)
__device__ __forceinline__ unsigned splitf2(float f) {
  unsigned u = __float_as_uint(f);
  unsigned t = (u + 0x7fffu + ((u >> 16) & 1u)) & 0xffff0000u;
  float r = f - __uint_as_float(t);  // exact
  unsigned v = __float_as_uint(r);
  unsigned tv = v + 0x7fffu + ((v >> 16) & 1u);
  return (t >> 16) | (tv & 0xffff0000u);
}
// 3-term split: hm = hi|mid packed u32, lo = third bf16 term
__device__ __forceinline__ void splitf3(float f, unsigned& hm,
                                        unsigned short& lo) {
  unsigned u = __float_as_uint(f);
  unsigned t = (u + 0x7fffu + ((u >> 16) & 1u)) & 0xffff0000u;
  float r1 = f - __uint_as_float(t);  // exact
  unsigned v = __float_as_uint(r1);
  unsigned tv = (v + 0x7fffu + ((v >> 16) & 1u)) & 0xffff0000u;
  float r2 = r1 - __uint_as_float(tv);  // exact
  unsigned w = __float_as_uint(r2);
  unsigned tw = w + 0x7fffu + ((w >> 16) & 1u);
  hm = (t >> 16) | tv;
  lo = (unsigned short)(tw >> 16);
}

__device__ __forceinline__ void unpack_hm(const unsigned* p, short8& h,
                                          short8& l) {
  const uint4 X = *(const uint4*)p;
  const uint4 Y = *(const uint4*)(p + 4);
  U16 Hh, Ll;
  Hh.u[0] = (X.x & 0xffffu) | (X.y << 16);
  Hh.u[1] = (X.z & 0xffffu) | (X.w << 16);
  Hh.u[2] = (Y.x & 0xffffu) | (Y.y << 16);
  Hh.u[3] = (Y.z & 0xffffu) | (Y.w << 16);
  Ll.u[0] = (X.x >> 16) | (X.y & 0xffff0000u);
  Ll.u[1] = (X.z >> 16) | (X.w & 0xffff0000u);
  Ll.u[2] = (Y.x >> 16) | (Y.y & 0xffff0000u);
  Ll.u[3] = (Y.z >> 16) | (Y.w & 0xffff0000u);
  h = Hh.s;
  l = Ll.s;
}

// ---------- NKAT per-token factor ----------
__global__ __launch_bounds__(64) void factor_kernel(
    const float* __restrict__ x, const float* __restrict__ alpha_p,
    const float* __restrict__ beta_p, float* __restrict__ fac) {
  const int row = blockIdx.x;
  const int lane = threadIdx.x;
  const float4* xr = (const float4*)(x + (size_t)row * C_);
  float s = 0.f, ss = 0.f;
#pragma unroll
  for (int j = 0; j < 4; ++j) {
    float4 v = xr[lane + 64 * j];
    s += v.x + v.y + v.z + v.w;
    ss += v.x * v.x + v.y * v.y + v.z * v.z + v.w * v.w;
  }
  s = wsumf(s);
  ss = wsumf(ss);
  const float mean = s * (1.f / 1024.f);
  const float var = ss * (1.f / 1024.f) - mean * mean;
  const float theta =
      alpha_p[0] * tanhf(mean) + beta_p[0] * (1.f / (1.f + __expf(-var)));
  if (lane == 0) fac[row] = 1.f + 0.45125f * theta;  // lc = 0.5*0.95^2
}

// ---------- 3-term split-bf16 MFMA core (q/k precision, ~2^-25) ----------
// 6 products {h*l, l*h, m*m, h*m, m*h, h*h}, accumulated smallest-first.
__device__ __forceinline__ void mfma_core6(
    const float* __restrict__ A, const float* __restrict__ Bm, int lda,
    int ldb, int m0, int n0, unsigned* a_hm, unsigned* b_hm,
    unsigned short* a_lo, unsigned short* b_lo, f32x4 acc[4][4]) {
  const int tid = threadIdx.x;
  const int lane = tid & 63;
  const int wm = ((tid >> 7) & 1) * 64;
  const int wn = ((tid >> 6) & 1) * 64;
  const int a_k4 = (tid & 7) * 4, a_m = tid >> 3;
  const int b_n4 = (tid & 31) * 4, b_k = (tid >> 5) * 4;
  const int fr = lane & 15, fk = (lane >> 4) * 8;

  float4 aR[4], bR[4];
#pragma unroll
  for (int j = 0; j < 4; ++j)
    aR[j] = *(const float4*)(A + (size_t)(m0 + a_m + 32 * j) * lda + a_k4);
#pragma unroll
  for (int i = 0; i < 4; ++i)
    bR[i] = *(const float4*)(Bm + (size_t)(b_k + i) * ldb + n0 + b_n4);

  for (int kt = 0; kt < 32; ++kt) {
    __syncthreads();
#pragma unroll
    for (int j = 0; j < 4; ++j) {
      uint4 w;
      ushort4 l;
      splitf3(aR[j].x, w.x, l.x);
      splitf3(aR[j].y, w.y, l.y);
      splitf3(aR[j].z, w.z, l.z);
      splitf3(aR[j].w, w.w, l.w);
      *(uint4*)(a_hm + (a_m + 32 * j) * KPAD + a_k4) = w;
      *(ushort4*)(a_lo + (a_m + 32 * j) * KPADL + a_k4) = l;
    }
#pragma unroll
    for (int i = 0; i < 4; ++i) {
      unsigned hm;
      unsigned short lo;
      splitf3(bR[i].x, hm, lo);
      b_hm[(b_n4 + 0) * KPAD + b_k + i] = hm;
      b_lo[(b_n4 + 0) * KPADL + b_k + i] = lo;
      splitf3(bR[i].y, hm, lo);
      b_hm[(b_n4 + 1) * KPAD + b_k + i] = hm;
      b_lo[(b_n4 + 1) * KPADL + b_k + i] = lo;
      splitf3(bR[i].z, hm, lo);
      b_hm[(b_n4 + 2) * KPAD + b_k + i] = hm;
      b_lo[(b_n4 + 2) * KPADL + b_k + i] = lo;
      splitf3(bR[i].w, hm, lo);
      b_hm[(b_n4 + 3) * KPAD + b_k + i] = hm;
      b_lo[(b_n4 + 3) * KPADL + b_k + i] = lo;
    }
    __syncthreads();
    if (kt + 1 < 32) {
      const int kb = (kt + 1) * 32;
#pragma unroll
      for (int j = 0; j < 4; ++j)
        aR[j] =
            *(const float4*)(A + (size_t)(m0 + a_m + 32 * j) * lda + kb + a_k4);
#pragma unroll
      for (int i = 0; i < 4; ++i)
        bR[i] = *(const float4*)(Bm + (size_t)(kb + b_k + i) * ldb + n0 + b_n4);
    }
    short8 ah[4], am[4], al[4];
#pragma unroll
    for (int rt = 0; rt < 4; ++rt) {
      const int row = wm + rt * 16 + fr;
      unpack_hm(a_hm + row * KPAD + fk, ah[rt], am[rt]);
      U16 L;
      L.q = *(const uint4*)(a_lo + row * KPADL + fk);
      al[rt] = L.s;
    }
#pragma unroll
    for (int ct = 0; ct < 4; ++ct) {
      const int row = wn + ct * 16 + fr;
      short8 bh, bm, bl;
      unpack_hm(b_hm + row * KPAD + fk, bh, bm);
      U16 L;
      L.q = *(const uint4*)(b_lo + row * KPADL + fk);
      bl = L.s;
#pragma unroll
      for (int rt = 0; rt < 4; ++rt) {
        f32x4 c = acc[rt][ct];
        c = __builtin_amdgcn_mfma_f32_16x16x32_bf16(ah[rt], bl, c, 0, 0, 0);
        c = __builtin_amdgcn_mfma_f32_16x16x32_bf16(al[rt], bh, c, 0, 0, 0);
        c = __builtin_amdgcn_mfma_f32_16x16x32_bf16(am[rt], bm, c, 0, 0, 0);
        c = __builtin_amdgcn_mfma_f32_16x16x32_bf16(ah[rt], bm, c, 0, 0, 0);
        c = __builtin_amdgcn_mfma_f32_16x16x32_bf16(am[rt], bh, c, 0, 0, 0);
        c = __builtin_amdgcn_mfma_f32_16x16x32_bf16(ah[rt], bh, c, 0, 0, 0);
        acc[rt][ct] = c;
      }
    }
  }
}

// ---------- 2-term split-bf16 MFMA core (v / out-proj, ~2^-18) ----------
// 3 products {h*l, l*h, h*h}, smallest-first.
__device__ __forceinline__ void mfma_core3(const float* __restrict__ A,
                                           const float* __restrict__ Bm,
                                           int lda, int ldb, int m0, int n0,
                                           unsigned* a_hm, unsigned* b_hm,
                                           f32x4 acc[4][4]) {
  const int tid = threadIdx.x;
  const int lane = tid & 63;
  const int wm = ((tid >> 7) & 1) * 64;
  const int wn = ((tid >> 6) & 1) * 64;
  const int a_k4 = (tid & 7) * 4, a_m = tid >> 3;
  const int b_n4 = (tid & 31) * 4, b_k = (tid >> 5) * 4;
  const int fr = lane & 15, fk = (lane >> 4) * 8;

  float4 aR[4], bR[4];
#pragma unroll
  for (int j = 0; j < 4; ++j)
    aR[j] = *(const float4*)(A + (size_t)(m0 + a_m + 32 * j) * lda + a_k4);
#pragma unroll
  for (int i = 0; i < 4; ++i)
    bR[i] = *(const float4*)(Bm + (size_t)(b_k + i) * ldb + n0 + b_n4);

  for (int kt = 0; kt < 32; ++kt) {
    __syncthreads();
#pragma unroll
    for (int j = 0; j < 4; ++j) {
      uint4 w;
      w.x = splitf2(aR[j].x);
      w.y = splitf2(aR[j].y);
      w.z = splitf2(aR[j].z);
      w.w = splitf2(aR[j].w);
      *(uint4*)(a_hm + (a_m + 32 * j) * KPAD + a_k4) = w;
    }
#pragma unroll
    for (int i = 0; i < 4; ++i) {
      unsigned* bp = b_hm + b_k + i;
      bp[(b_n4 + 0) * KPAD] = splitf2(bR[i].x);
      bp[(b_n4 + 1) * KPAD] = splitf2(bR[i].y);
      bp[(b_n4 + 2) * KPAD] = splitf2(bR[i].z);
      bp[(b_n4 + 3) * KPAD] = splitf2(bR[i].w);
    }
    __syncthreads();
    if (kt + 1 < 32) {
      const int kb = (kt + 1) * 32;
#pragma unroll
      for (int j = 0; j < 4; ++j)
        aR[j] =
            *(const float4*)(A + (size_t)(m0 + a_m + 32 * j) * lda + kb + a_k4);
#pragma unroll
      for (int i = 0; i < 4; ++i)
        bR[i] = *(const float4*)(Bm + (size_t)(kb + b_k + i) * ldb + n0 + b_n4);
    }
    short8 ah[4], al[4];
#pragma unroll
    for (int rt = 0; rt < 4; ++rt)
      unpack_hm(a_hm + (wm + rt * 16 + fr) * KPAD + fk, ah[rt], al[rt]);
#pragma unroll
    for (int ct = 0; ct < 4; ++ct) {
      short8 bh, bl;
      unpack_hm(b_hm + (wn + ct * 16 + fr) * KPAD + fk, bh, bl);
#pragma unroll
      for (int rt = 0; rt < 4; ++rt) {
        f32x4 c = acc[rt][ct];
        c = __builtin_amdgcn_mfma_f32_16x16x32_bf16(ah[rt], bl, c, 0, 0, 0);
        c = __builtin_amdgcn_mfma_f32_16x16x32_bf16(al[rt], bh, c, 0, 0, 0);
        c = __builtin_amdgcn_mfma_f32_16x16x32_bf16(ah[rt], bh, c, 0, 0, 0);
        acc[rt][ct] = c;
      }
    }
  }
}

// ---------- qk: columns 0..2047 of x@w_qkv -> q (B,H,N,HD) and kt [bh][d][n] ----------
__global__ __launch_bounds__(256) void gemm_qk_kernel(
    const float* __restrict__ x, const float* __restrict__ w,
    float* __restrict__ q, float* __restrict__ ktb) {
  __shared__ unsigned a_hm[128 * KPAD];
  __shared__ unsigned b_hm[128 * KPAD];
  __shared__ unsigned short a_lo[128 * KPADL];
  __shared__ unsigned short b_lo[128 * KPADL];
  f32x4 acc[4][4];
#pragma unroll
  for (int i = 0; i < 4; ++i)
#pragma unroll
    for (int j = 0; j < 4; ++j) acc[i][j] = (f32x4){0.f, 0.f, 0.f, 0.f};
  const int m0 = blockIdx.y * 128, n0 = blockIdx.x * 128;
  mfma_core6(x, w, C_, 3 * C_, m0, n0, a_hm, b_hm, a_lo, b_lo, acc);

  const int lane = threadIdx.x & 63;
  const int wm = ((threadIdx.x >> 7) & 1) * 64;
  const int wn = ((threadIdx.x >> 6) & 1) * 64;
  const int rbase = (lane >> 4) * 4, cc = lane & 15;
#pragma unroll
  for (int rt = 0; rt < 4; ++rt) {
    const int m = m0 + wm + rt * 16 + rbase;
    const int bb = m >> 10, nn = m & 1023;
#pragma unroll
    for (int ct = 0; ct < 4; ++ct) {
      const int j = n0 + wn + ct * 16 + cc;
      const int sel = j >> 10, hh = (j >> 6) & 15, d0 = j & 63;
      const f32x4 c = acc[rt][ct];
      if (sel == 1) {  // K transposed: contiguous along token index nn
        *(float4*)(ktb + (((size_t)(bb * 16 + hh) * HD_ + d0) << 10) + nn) =
            make_float4(c[0], c[1], c[2], c[3]);
      } else {
        float* dst = q + (((size_t)(bb * 16 + hh) << 10) + nn) * HD_ + d0;
        dst[0] = c[0];
        dst[HD_] = c[1];
        dst[2 * HD_] = c[2];
        dst[3 * HD_] = c[3];
      }
    }
  }
}

// ---------- v: columns 2048..3071 -> v (B,H,N,HD) ----------
__global__ __launch_bounds__(256) void gemm_v_kernel(
    const float* __restrict__ x, const float* __restrict__ w,
    float* __restrict__ v) {
  __shared__ unsigned a_hm[128 * KPAD];
  __shared__ unsigned b_hm[128 * KPAD];
  f32x4 acc[4][4];
#pragma unroll
  for (int i = 0; i < 4; ++i)
#pragma unroll
    for (int j = 0; j < 4; ++j) acc[i][j] = (f32x4){0.f, 0.f, 0.f, 0.f};
  const int m0 = blockIdx.y * 128, n0 = 2048 + blockIdx.x * 128;
  mfma_core3(x, w, C_, 3 * C_, m0, n0, a_hm, b_hm, acc);

  const int lane = threadIdx.x & 63;
  const int wm = ((threadIdx.x >> 7) & 1) * 64;
  const int wn = ((threadIdx.x >> 6) & 1) * 64;
  const int rbase = (lane >> 4) * 4, cc = lane & 15;
#pragma unroll
  for (int rt = 0; rt < 4; ++rt) {
    const int m = m0 + wm + rt * 16 + rbase;
    const int bb = m >> 10, nn = m & 1023;
#pragma unroll
    for (int ct = 0; ct < 4; ++ct) {
      const int jv = (n0 - 2048) + wn + ct * 16 + cc;
      const int hh = (jv >> 6) & 15, d0 = jv & 63;
      const f32x4 c = acc[rt][ct];
      float* dst = v + (((size_t)(bb * 16 + hh) << 10) + nn) * HD_ + d0;
      dst[0] = c[0];
      dst[HD_] = c[1];
      dst[2 * HD_] = c[2];
      dst[3 * HD_] = c[3];
    }
  }
}

// ---------- out = attn_out @ w_out + b_out ----------
__global__ __launch_bounds__(256) void gemm_out_kernel(
    const float* __restrict__ a, const float* __restrict__ w,
    const float* __restrict__ bias, float* __restrict__ out) {
  __shared__ unsigned a_hm[128 * KPAD];
  __shared__ unsigned b_hm[128 * KPAD];
  f32x4 acc[4][4];
#pragma unroll
  for (int i = 0; i < 4; ++i)
#pragma unroll
    for (int j = 0; j < 4; ++j) acc[i][j] = (f32x4){0.f, 0.f, 0.f, 0.f};
  const int m0 = blockIdx.y * 128, n0 = blockIdx.x * 128;
  mfma_core3(a, w, C_, C_, m0, n0, a_hm, b_hm, acc);

  const int lane = threadIdx.x & 63;
  const int wm = ((threadIdx.x >> 7) & 1) * 64;
  const int wn = ((threadIdx.x >> 6) & 1) * 64;
  const int rbase = (lane >> 4) * 4, cc = lane & 15;
#pragma unroll
  for (int rt = 0; rt < 4; ++rt) {
    const int m = m0 + wm + rt * 16 + rbase;
#pragma unroll
    for (int ct = 0; ct < 4; ++ct) {
      const int j = n0 + wn + ct * 16 + cc;
      const float bj = bias[j];
      const f32x4 c = acc[rt][ct];
      float* dst = out + (size_t)m * C_ + j;
      dst[0] = c[0] + bj;
      dst[C_] = c[1] + bj;
      dst[2 * C_] = c[2] + bj;
      dst[3 * C_] = c[3] + bj;
    }
  }
}

// ---------- attention: round-8 kernel, unchanged (verified) ----------
__global__ __launch_bounds__(256) void attn_kernel(
    const float* __restrict__ qw, const float* __restrict__ kt,
    const float* __restrict__ vw, const float* __restrict__ fac,
    float* __restrict__ ao) {
  const int lane = threadIdx.x & 63;
  const int wid = threadIdx.x >> 6;
  const int qblk = blockIdx.x * 16;
  const int bh = qblk >> 10;
  const int b = bh >> 4, h = bh & 15;
  const int q0 = (qblk & (N_ - 1)) + wid * 4;

  __shared__ __align__(16) float q_ldsT[4][HD_][4];
  __shared__ unsigned su[4][64];
  __shared__ float sv[4][64];
  __shared__ int ck[4][64];
  __shared__ float cv[4][64];

  {
    const int qq = lane >> 4, dp = (lane & 15) << 2;
    const float4 v =
        *(const float4*)(qw + ((size_t)bh * N_ + q0 + qq) * HD_ + dp);
    q_ldsT[wid][dp + 0][qq] = v.x;
    q_ldsT[wid][dp + 1][qq] = v.y;
    q_ldsT[wid][dp + 2][qq] = v.z;
    q_ldsT[wid][dp + 3][qq] = v.w;
  }

  const float* ktb = kt + ((size_t)bh * HD_ * N_);
  const unsigned long long ltmask = (1ull << lane) - 1ull;
  unsigned u[4][16];

  for (int pass = 0; pass < 4; ++pass) {
    float acc[4][4];
#pragma unroll
    for (int a = 0; a < 4; ++a)
#pragma unroll
      for (int c = 0; c < 4; ++c) acc[a][c] = 0.f;
    const float* kp = ktb + (pass << 8) + (lane << 2);
#pragma unroll 4
    for (int d = 0; d < HD_; ++d) {
      const float4 kv = *(const float4*)(kp + (size_t)d * N_);
      const float4 qv = *(const float4*)(&q_ldsT[wid][d][0]);
      acc[0][0] = fmaf(kv.x, qv.x, acc[0][0]);
      acc[0][1] = fmaf(kv.x, qv.y, acc[0][1]);
      acc[0][2] = fmaf(kv.x, qv.z, acc[0][2]);
      acc[0][3] = fmaf(kv.x, qv.w, acc[0][3]);
      acc[1][0] = fmaf(kv.y, qv.x, acc[1][0]);
      acc[1][1] = fmaf(kv.y, qv.y, acc[1][1]);
      acc[1][2] = fmaf(kv.y, qv.z, acc[1][2]);
      acc[1][3] = fmaf(kv.y, qv.w, acc[1][3]);
      acc[2][0] = fmaf(kv.z, qv.x, acc[2][0]);
      acc[2][1] = fmaf(kv.z, qv.y, acc[2][1]);
      acc[2][2] = fmaf(kv.z, qv.z, acc[2][2]);
      acc[2][3] = fmaf(kv.z, qv.w, acc[2][3]);
      acc[3][0] = fmaf(kv.w, qv.x, acc[3][0]);
      acc[3][1] = fmaf(kv.w, qv.y, acc[3][1]);
      acc[3][2] = fmaf(kv.w, qv.z, acc[3][2]);
      acc[3][3] = fmaf(kv.w, qv.w, acc[3][3]);
    }
#pragma unroll
    for (int jl = 0; jl < 4; ++jl)
#pragma unroll
      for (int q = 0; q < 4; ++q)
        u[q][(pass << 2) + jl] = orderu((acc[jl][q] * 0.125f) / 0.8f);
  }

  unsigned mu[4], l0[4];
#pragma unroll
  for (int q = 0; q < 4; ++q) {
    unsigned mq = u[q][0];
#pragma unroll
    for (int j = 1; j < 16; ++j) mq = max(mq, u[q][j]);
    mu[q] = mq;
    l0[q] = mq;
  }
#pragma unroll
  for (int off = 32; off; off >>= 1) {
#pragma unroll
    for (int q = 0; q < 4; ++q) {
      mu[q] = max(mu[q], (unsigned)__shfl_xor((int)mu[q], off, 64));
      l0[q] = min(l0[q], (unsigned)__shfl_xor((int)l0[q], off, 64));
    }
  }

  unsigned lo[4], hi[4];
#pragma unroll
  for (int q = 0; q < 4; ++q) {
    lo[q] = l0[q];
    hi[q] = mu[q];
  }
  while ((lo[0] < hi[0]) | (lo[1] < hi[1]) | (lo[2] < hi[2]) |
         (lo[3] < hi[3])) {
#pragma unroll
    for (int q = 0; q < 4; ++q) {
      if (lo[q] < hi[q]) {
        const unsigned mid = lo[q] + ((hi[q] - lo[q]) >> 1) + 1u;
        int c = 0;
#pragma unroll
        for (int j = 0; j < 16; ++j)
          c += (int)__popcll(__ballot(u[q][j] >= mid));
        if (c >= 64) lo[q] = mid;
        else hi[q] = mid - 1u;
      }
    }
  }

  const float* vb = vw + ((size_t)bh << 16);
#pragma unroll
  for (int qq = 0; qq < 4; ++qq) {
    const unsigned kthu = lo[qq];
    const float m = iorderu(mu[qq]);

    float e[16];
    float zl = 0.f;
#pragma unroll
    for (int j = 0; j < 16; ++j) {
      const float ej = (u[qq][j] >= kthu) ? __expf(iorderu(u[qq][j]) - m) : 0.f;
      e[j] = ej;
      zl += ej;
    }
    const float Z = wsumf(zl);
    const float limit = 0.9f * Z;

    int base = 0;
#pragma unroll
    for (int j = 0; j < 16; ++j) {
      const bool f = (u[qq][j] >= kthu);
      const unsigned long long mb = __ballot(f);
      if (f) {
        const int pos = base + (int)__popcll(mb & ltmask);
        if (pos < 64) {
          su[wid][pos] = u[qq][j];
          sv[wid][pos] = e[j];
        }
      }
      base += (int)__popcll(mb);
    }

    unsigned sk = ~su[wid][lane];
    float se = sv[wid][lane];
#pragma unroll
    for (int k = 2; k <= 64; k <<= 1) {
#pragma unroll
      for (int j = k >> 1; j; j >>= 1) {
        const unsigned pk = (unsigned)__shfl_xor((int)sk, j, 64);
        const float pe = __shfl_xor(se, j, 64);
        const bool takeMin = (((lane & j) == 0) == ((lane & k) == 0));
        const bool sw = takeMin ? (pk < sk) : (pk > sk);
        if (sw) {
          sk = pk;
          se = pe;
        }
      }
    }

    float pre = se;
#pragma unroll
    for (int off = 1; off <= 32; off <<= 1) {
      const float t = __shfl_up(pre, off, 64);
      if (lane >= off) pre += t;
    }
    const float excl = pre - se;
    const bool keep = (excl <= limit);
    const unsigned long long km = __ballot(keep);
    const int L = 63 - __builtin_clzll(km);
    const unsigned thr = ~(unsigned)__shfl((int)sk, L, 64);

    float z2l = 0.f;
#pragma unroll
    for (int j = 0; j < 16; ++j) z2l += (u[qq][j] >= thr) ? e[j] : 0.f;
    const float Z2 = wsumf(z2l);
    const float wsc = fac[(b << 10) + q0 + qq] / Z2;

    int M = 0;
#pragma unroll
    for (int j = 0; j < 16; ++j) {
      const bool f = (u[qq][j] >= thr);
      const unsigned long long mb = __ballot(f);
      if (f) {
        const int pos = M + (int)__popcll(mb & ltmask);
        if (pos < 64) {
          ck[wid][pos] = ((j >> 2) << 8) + (lane << 2) + (j & 3);
          cv[wid][pos] = e[j] * wsc;
        }
      }
      M += (int)__popcll(mb);
    }
    if (M > 64) M = 64;

    float a0 = 0.f, a1 = 0.f, a2 = 0.f, a3 = 0.f;
    int i = 0;
    for (; i + 4 <= M; i += 4) {
      const int k0 = ck[wid][i], k1 = ck[wid][i + 1];
      const int k2 = ck[wid][i + 2], k3 = ck[wid][i + 3];
      const float c0 = cv[wid][i], c1 = cv[wid][i + 1];
      const float c2 = cv[wid][i + 2], c3 = cv[wid][i + 3];
      a0 = fmaf(c0, vb[((size_t)k0 << 6) + lane], a0);
      a1 = fmaf(c1, vb[((size_t)k1 << 6) + lane], a1);
      a2 = fmaf(c2, vb[((size_t)k2 << 6) + lane], a2);
      a3 = fmaf(c3, vb[((size_t)k3 << 6) + lane], a3);
    }
    for (; i < M; ++i)
      a0 = fmaf(cv[wid][i], vb[((size_t)ck[wid][i] << 6) + lane], a0);
    const float o = (a0 + a1) + (a2 + a3);

    ao[(((size_t)b << 10) + q0 + qq) * C_ + (h << 6) + lane] = o;
  }
}

extern "C" void kernel_launch(void* const* d_in, const int* in_sizes, int n_in,
                              void* d_out, int out_size, void* d_ws,
                              size_t ws_size, hipStream_t stream) {
  const float* x = (const float*)d_in[0];
  const float* wqkv = (const float*)d_in[1];
  const float* wout = (const float*)d_in[2];
  const float* bout = (const float*)d_in[3];
  const float* alpha = (const float*)d_in[4];
  const float* beta = (const float*)d_in[5];
  float* out = (float*)d_out;

  float* ws = (float*)d_ws;
  const size_t SZ = (size_t)B_ * H_ * N_ * HD_;  // 2M floats
  float* qw = ws;
  float* kt = ws + SZ;  // K transposed per head: [bh][d][n]
  float* vw = ws + 2 * SZ;
  float* ao = ws + 3 * SZ;
  float* fc = ws + 4 * SZ;

  factor_kernel<<<B_ * N_, 64, 0, stream>>>(x, alpha, beta, fc);
  gemm_qk_kernel<<<dim3(16, 16), 256, 0, stream>>>(x, wqkv, qw, kt);
  gemm_v_kernel<<<dim3(8, 16), 256, 0, stream>>>(x, wqkv, vw);
  attn_kernel<<<(B_ * H_ * N_) / 16, 256, 0, stream>>>(qw, kt, vw, fc, ao);
  gemm_out_kernel<<<dim3(8, 16), 256, 0, stream>>>(ao, wout, bout, out);
}